// Round 1
// baseline (748.498 us; speedup 1.0000x reference)
//
#include <hip/hip_runtime.h>
#include <cmath>

#define Bb 32
#define Dm 4096
#define Hh 32
#define HKVh 8
#define HD 128
#define Gq 4
#define MAXLEN 2048
#define NQ 4096
#define NKV 1024
#define NTOT 6144
#define KSPLIT 8
#define KCH 512
#define LSPLIT 4
#define SCALE 0.08838834764831845f

__device__ __forceinline__ float4 fma4(float s, float4 w, float4 a) {
    a.x = fmaf(s, w.x, a.x); a.y = fmaf(s, w.y, a.y);
    a.z = fmaf(s, w.z, a.z); a.w = fmaf(s, w.w, a.w);
    return a;
}

// ---------- Kernel 1: qkv split-K partial GEMM: part[ks][b][NTOT] ----------
__global__ __launch_bounds__(256) void k_qkv(const float* __restrict__ x,
    const float* __restrict__ wq, const float* __restrict__ wk,
    const float* __restrict__ wv, float* __restrict__ part)
{
    __shared__ float xs[Bb][KCH];   // 64 KB
    const int ct = blockIdx.x;      // 0..95 column tile (64 cols)
    const int ks = blockIdx.y;      // 0..7 k-split
    const int c0 = ct * 64;
    const int k0 = ks * KCH;
    const float* Wp; int ldw; int cw;
    if (c0 < NQ)          { Wp = wq; ldw = NQ;  cw = c0; }
    else if (c0 < NQ+NKV) { Wp = wk; ldw = NKV; cw = c0 - NQ; }
    else                  { Wp = wv; ldw = NKV; cw = c0 - NQ - NKV; }

    const int t = threadIdx.x;
    for (int i = t; i < Bb * (KCH/4); i += 256) {
        int b = i >> 7;
        int kk = (i & 127) << 2;
        float4 v4 = *(const float4*)(x + (size_t)b*Dm + k0 + kk);
        xs[b][kk+0] = v4.x; xs[b][kk+1] = v4.y; xs[b][kk+2] = v4.z; xs[b][kk+3] = v4.w;
    }
    __syncthreads();

    const int cg = t & 15;          // 16 col-groups of 4 cols
    const int bg = t >> 4;          // 16 batch-groups of 2 batches
    const int b0 = bg * 2;
    const float* wp = Wp + (size_t)k0 * ldw + cw + cg*4;
    float4 a0 = make_float4(0.f,0.f,0.f,0.f), a1 = make_float4(0.f,0.f,0.f,0.f);
#pragma unroll 2
    for (int k = 0; k < KCH; k += 4) {
        float4 w0 = *(const float4*)(wp);
        float4 w1 = *(const float4*)(wp + ldw);
        float4 w2 = *(const float4*)(wp + 2*ldw);
        float4 w3 = *(const float4*)(wp + 3*ldw);
        wp += 4*ldw;
        float4 xa = *(const float4*)(&xs[b0][k]);
        float4 xb = *(const float4*)(&xs[b0+1][k]);
        a0 = fma4(xa.x, w0, a0); a1 = fma4(xb.x, w0, a1);
        a0 = fma4(xa.y, w1, a0); a1 = fma4(xb.y, w1, a1);
        a0 = fma4(xa.z, w2, a0); a1 = fma4(xb.z, w2, a1);
        a0 = fma4(xa.w, w3, a0); a1 = fma4(xb.w, w3, a1);
    }
    size_t base = ((size_t)ks * Bb + b0) * NTOT + c0 + cg*4;
    *(float4*)(part + base) = a0;
    *(float4*)(part + base + NTOT) = a1;
}

// ---------- Kernel 2: reduce split-K + RoPE + scatter to caches / qbuf ----------
__global__ __launch_bounds__(256) void k_rope_scatter(const float* __restrict__ part,
    const float* __restrict__ cos_, const float* __restrict__ sin_,
    const int* __restrict__ start_pos, float* __restrict__ qbuf,
    float* __restrict__ cache_k, float* __restrict__ cache_v)
{
    int idx = blockIdx.x*256 + threadIdx.x;   // pair id, 98304 total
    int b  = idx / (NTOT/2);
    int cp = idx % (NTOT/2);
    int c = cp*2;
    float xr = 0.f, xi = 0.f;
#pragma unroll
    for (int s = 0; s < KSPLIT; ++s) {
        const float2 p = *(const float2*)(part + ((size_t)s*Bb + b)*NTOT + c);
        xr += p.x; xi += p.y;
    }
    const int sp = start_pos[0];
    if (c < NQ) {
        int h = c / HD, dd = c % HD; int fi = dd >> 1;
        float co = cos_[fi], si = sin_[fi];
        float2 o = make_float2(xr*co - xi*si, xr*si + xi*co);
        *(float2*)(qbuf + ((size_t)b*Hh + h)*HD + dd) = o;
    } else if (c < NQ+NKV) {
        int cc = c - NQ; int h = cc / HD, dd = cc % HD; int fi = dd >> 1;
        float co = cos_[fi], si = sin_[fi];
        float2 o = make_float2(xr*co - xi*si, xr*si + xi*co);
        *(float2*)(cache_k + (((size_t)b*HKVh + h)*MAXLEN + sp)*HD + dd) = o;
    } else {
        int cc = c - NQ - NKV; int h = cc / HD, dd = cc % HD;
        *(float2*)(cache_v + (((size_t)b*HKVh + h)*MAXLEN + sp)*HD + dd) = make_float2(xr, xi);
    }
}

// ---------- Kernel 3: flash-decode attention, L-split partials ----------
__global__ __launch_bounds__(512) void k_attn(const float* __restrict__ qbuf,
    const float* __restrict__ cache_k, const float* __restrict__ cache_v,
    const int* __restrict__ start_pos, float* __restrict__ pout)
{
    __shared__ float sbuf[Gq][128];
    __shared__ float mrun[Gq], lrun[Gq], alphaS[Gq];
    __shared__ float pbuf[4][Gq][HD];

    const int bk = blockIdx.x;
    const int b  = bk >> 3;
    const int kv = bk & 7;
    const int sp = blockIdx.y;
    const int L  = start_pos[0] + 1;
    const int per = (L + LSPLIT - 1) / LSPLIT;
    const int p0 = sp * per;
    const int p1 = min(L, p0 + per);

    const int t = threadIdx.x;
    const int wave = t >> 6;
    const int lane = t & 63;
    const int half = lane >> 5;
    const int dl = lane & 31;

    float4 q4[Gq];
#pragma unroll
    for (int g = 0; g < Gq; ++g)
        q4[g] = *(const float4*)(qbuf + ((size_t)b*Hh + kv*Gq + g)*HD + dl*4);

    const float* kbase = cache_k + ((size_t)b*HKVh + kv)*MAXLEN*HD;
    const float* vbase = cache_v + ((size_t)b*HKVh + kv)*MAXLEN*HD;

    const int dC = t & 127;
    const int psC = t >> 7;
    float acc[Gq] = {0.f,0.f,0.f,0.f};

    if (t < Gq) { mrun[t] = -INFINITY; lrun[t] = 0.f; }
    __syncthreads();

    for (int c0 = p0; c0 < p1; c0 += 128) {
        const int CP = min(128, p1 - c0);
        // Phase A: scores for 128 positions
        for (int j = wave; j < 64; j += 8) {
            int p = c0 + 2*j + half;
            int pc = p < p1 ? p : (p1 - 1);
            float4 k4 = *(const float4*)(kbase + (size_t)pc*HD + dl*4);
            float s0 = q4[0].x*k4.x + q4[0].y*k4.y + q4[0].z*k4.z + q4[0].w*k4.w;
            float s1 = q4[1].x*k4.x + q4[1].y*k4.y + q4[1].z*k4.z + q4[1].w*k4.w;
            float s2 = q4[2].x*k4.x + q4[2].y*k4.y + q4[2].z*k4.z + q4[2].w*k4.w;
            float s3 = q4[3].x*k4.x + q4[3].y*k4.y + q4[3].z*k4.z + q4[3].w*k4.w;
#pragma unroll
            for (int off = 16; off; off >>= 1) {
                s0 += __shfl_xor(s0, off, 32);
                s1 += __shfl_xor(s1, off, 32);
                s2 += __shfl_xor(s2, off, 32);
                s3 += __shfl_xor(s3, off, 32);
            }
            if (dl == 0) {
                int slot = 2*j + half;
                bool ok = (p < p1);
                sbuf[0][slot] = ok ? s0*SCALE : -INFINITY;
                sbuf[1][slot] = ok ? s1*SCALE : -INFINITY;
                sbuf[2][slot] = ok ? s2*SCALE : -INFINITY;
                sbuf[3][slot] = ok ? s3*SCALE : -INFINITY;
            }
        }
        __syncthreads();
        // Phase B: online softmax (waves 0..3, one per head)
        if (wave < Gq) {
            int g = wave;
            float s0 = sbuf[g][lane];
            float s1 = sbuf[g][lane + 64];
            float mloc = fmaxf(s0, s1);
#pragma unroll
            for (int off = 32; off; off >>= 1) mloc = fmaxf(mloc, __shfl_xor(mloc, off));
            float mold = mrun[g];
            float mnew = fmaxf(mold, mloc);
            float e0 = __expf(s0 - mnew);
            float e1 = __expf(s1 - mnew);
            sbuf[g][lane]      = e0;
            sbuf[g][lane + 64] = e1;
            float ssum = e0 + e1;
#pragma unroll
            for (int off = 32; off; off >>= 1) ssum += __shfl_xor(ssum, off);
            if (lane == 0) {
                float alpha = (mold == -INFINITY) ? 0.f : __expf(mold - mnew);
                alphaS[g] = alpha;
                lrun[g] = lrun[g]*alpha + ssum;
                mrun[g] = mnew;
            }
        }
        __syncthreads();
        // Phase C: PV accumulate (coalesced direct v reads)
        {
#pragma unroll
            for (int g = 0; g < Gq; ++g) acc[g] *= alphaS[g];
            for (int p = c0 + psC; p < c0 + CP; p += 4) {
                float vv = vbase[(size_t)p*HD + dC];
#pragma unroll
                for (int g = 0; g < Gq; ++g)
                    acc[g] = fmaf(sbuf[g][p - c0], vv, acc[g]);
            }
        }
        __syncthreads();
    }
    // combine p_sub partials, write split output
#pragma unroll
    for (int g = 0; g < Gq; ++g) pbuf[psC][g][dC] = acc[g];
    __syncthreads();
    float* po = pout + (size_t)(bk * LSPLIT + sp) * (Gq*HD + 2*Gq);
    {
        int g = t >> 7, d = t & 127;
        float s = pbuf[0][g][d] + pbuf[1][g][d] + pbuf[2][g][d] + pbuf[3][g][d];
        po[g*HD + d] = s;
    }
    if (t < Gq) { po[Gq*HD + t] = mrun[t]; po[Gq*HD + Gq + t] = lrun[t]; }
}

// ---------- Kernel 4: combine L-splits -> attn_out [b][h][d] ----------
__global__ __launch_bounds__(256) void k_comb(const float* __restrict__ pout,
    float* __restrict__ attn)
{
    int idx = blockIdx.x*256 + threadIdx.x;   // 131072
    int d = idx & 127;
    int h = (idx >> 7) & 31;
    int b = idx >> 12;
    int kv = h >> 2, g = h & 3;
    int bk = b*8 + kv;
    const float* base = pout + (size_t)bk * LSPLIT * (Gq*HD + 2*Gq);
    float m = -INFINITY;
#pragma unroll
    for (int s = 0; s < LSPLIT; ++s) m = fmaxf(m, base[s*520 + 512 + g]);
    float num = 0.f, den = 0.f;
#pragma unroll
    for (int s = 0; s < LSPLIT; ++s) {
        float ms = base[s*520 + 512 + g];
        float ls = base[s*520 + 516 + g];
        float w = (ms == -INFINITY) ? 0.f : __expf(ms - m);
        num = fmaf(w, base[s*520 + g*HD + d], num);
        den = fmaf(w, ls, den);
    }
    attn[idx] = num / den;
}

// ---------- Kernel 5: out-projection split-K partial: part[ks][b][4096] ----------
__global__ __launch_bounds__(256) void k_proj(const float* __restrict__ inp,
    const float* __restrict__ W, float* __restrict__ part)
{
    __shared__ float xs[Bb][KCH];
    const int ct = blockIdx.x;      // 0..63
    const int ks = blockIdx.y;
    const int c0 = ct * 64;
    const int k0 = ks * KCH;

    const int t = threadIdx.x;
    for (int i = t; i < Bb * (KCH/4); i += 256) {
        int b = i >> 7;
        int kk = (i & 127) << 2;
        float4 v4 = *(const float4*)(inp + (size_t)b*NQ + k0 + kk);
        xs[b][kk+0] = v4.x; xs[b][kk+1] = v4.y; xs[b][kk+2] = v4.z; xs[b][kk+3] = v4.w;
    }
    __syncthreads();

    const int cg = t & 15;
    const int bg = t >> 4;
    const int b0 = bg * 2;
    const float* wp = W + (size_t)k0 * NQ + c0 + cg*4;
    float4 a0 = make_float4(0.f,0.f,0.f,0.f), a1 = make_float4(0.f,0.f,0.f,0.f);
#pragma unroll 2
    for (int k = 0; k < KCH; k += 4) {
        float4 w0 = *(const float4*)(wp);
        float4 w1 = *(const float4*)(wp + NQ);
        float4 w2 = *(const float4*)(wp + 2*NQ);
        float4 w3 = *(const float4*)(wp + 3*NQ);
        wp += 4*NQ;
        float4 xa = *(const float4*)(&xs[b0][k]);
        float4 xb = *(const float4*)(&xs[b0+1][k]);
        a0 = fma4(xa.x, w0, a0); a1 = fma4(xb.x, w0, a1);
        a0 = fma4(xa.y, w1, a0); a1 = fma4(xb.y, w1, a1);
        a0 = fma4(xa.z, w2, a0); a1 = fma4(xb.z, w2, a1);
        a0 = fma4(xa.w, w3, a0); a1 = fma4(xb.w, w3, a1);
    }
    size_t base = ((size_t)ks * Bb + b0) * NQ + c0 + cg*4;
    *(float4*)(part + base) = a0;
    *(float4*)(part + base + NQ) = a1;
}

// ---------- Kernel 6: reduce proj partials -> d_out ----------
__global__ __launch_bounds__(256) void k_red(const float* __restrict__ part,
    float* __restrict__ out)
{
    int idx = blockIdx.x*256 + threadIdx.x;   // 131072
    float s = 0.f;
#pragma unroll
    for (int k = 0; k < KSPLIT; ++k) s += part[(size_t)k*Bb*NQ + idx];
    out[idx] = s;
}

extern "C" void kernel_launch(void* const* d_in, const int* in_sizes, int n_in,
                              void* d_out, int out_size, void* d_ws, size_t ws_size,
                              hipStream_t stream)
{
    const float* x  = (const float*)d_in[0];
    float* cache_k  = (float*)d_in[1];
    float* cache_v  = (float*)d_in[2];
    const float* wq = (const float*)d_in[3];
    const float* wk = (const float*)d_in[4];
    const float* wv = (const float*)d_in[5];
    const float* wo = (const float*)d_in[6];
    const float* fc = (const float*)d_in[7];
    const float* fs = (const float*)d_in[8];
    const int* sp   = (const int*)d_in[9];
    float* out      = (float*)d_out;

    float* ws = (float*)d_ws;
    float* qkv_part = ws;                       // 8*32*6144   = 1572864 f
    float* qbuf     = qkv_part + 1572864;       // 32*32*128   = 131072 f
    float* attn_prt = qbuf + 131072;            // 256*4*520   = 532480 f
    float* attn_out = attn_prt + 532480;        // 131072 f
    float* proj_prt = attn_out + 131072;        // 8*32*4096   = 1048576 f

    k_qkv<<<dim3(96, 8), 256, 0, stream>>>(x, wq, wk, wv, qkv_part);
    k_rope_scatter<<<dim3(384), 256, 0, stream>>>(qkv_part, fc, fs, sp, qbuf, cache_k, cache_v);
    k_attn<<<dim3(256, LSPLIT), 512, 0, stream>>>(qbuf, cache_k, cache_v, sp, attn_prt);
    k_comb<<<dim3(512), 256, 0, stream>>>(attn_prt, attn_out);
    k_proj<<<dim3(64, 8), 256, 0, stream>>>(attn_out, wo, proj_prt);
    k_red<<<dim3(512), 256, 0, stream>>>(proj_prt, out);
}